// Round 10
// baseline (23941.136 us; speedup 1.0000x reference)
//
#include <hip/hip_runtime.h>
#include <cmath>

#define HID 512
#define NEXP 128
#define BB 4
#define SS 2048
#define NROW (BB*SS)      // 8192
#define FAST_ITERS 96
#define FAIL_STICKY 16
#define WARMUP_T 16

typedef unsigned long long u64;
typedef unsigned int u32;
typedef unsigned int v4u __attribute__((ext_vector_type(4)));

__device__ __forceinline__ float gelu_f(float x){
  return 0.5f*x*(1.0f + erff(x*0.70710678118654752440f));
}

__device__ __forceinline__ u64 aload64(const u64* p){
  return __hip_atomic_load(p, __ATOMIC_RELAXED, __HIP_MEMORY_SCOPE_AGENT);
}
__device__ __forceinline__ void astore64(u64* p, u64 v){
  __hip_atomic_store(p, v, __ATOMIC_RELAXED, __HIP_MEMORY_SCOPE_AGENT);
}
__device__ __forceinline__ int aloadi(const int* p){
  return __hip_atomic_load(p, __ATOMIC_RELAXED, __HIP_MEMORY_SCOPE_AGENT);
}
__device__ __forceinline__ void fstore64(u64* p, u64 v){
  asm volatile("global_store_dwordx2 %0, %1, off" :: "v"(p), "v"(v) : "memory");
}
__device__ __forceinline__ u64 packtag(float f, u32 tag){
  return ((u64)__float_as_uint(f) << 32) | (u64)tag;
}

// per-WAVE poll of all 512 words: lane covers k = {2l,2l+1} + 128*i (i=0..3)
// fast = 4 dwordx4 sc0 loads issued together, ONE vmcnt(0); mirror fallback.
// deposits payloads into PADDED per-wave staging: ad = k + 2*(k>>SHIFT)
template<int SHIFT>
__device__ __forceinline__ void pollw(const u64* fb, const u64* mb, u32 tag,
                                      float* stgp, int l,
                                      int& fails, bool& use_agent, bool count){
  u32 pay[8];
  bool ok0=false, ok1=false, ok2=false, ok3=false;
  if (!use_agent){
    const u64* p0 = fb + l*2;
    const u64* p1 = fb + l*2 + 128;
    const u64* p2 = fb + l*2 + 256;
    const u64* p3 = fb + l*2 + 384;
    for (int it = 0; it < FAST_ITERS; ++it){
      v4u x0, x1, x2, x3;
      asm volatile("global_load_dwordx4 %0, %4, off sc0\n\t"
                   "global_load_dwordx4 %1, %5, off sc0\n\t"
                   "global_load_dwordx4 %2, %6, off sc0\n\t"
                   "global_load_dwordx4 %3, %7, off sc0\n\t"
                   "s_waitcnt vmcnt(0)"
                   : "=&v"(x0), "=&v"(x1), "=&v"(x2), "=&v"(x3)
                   : "v"(p0), "v"(p1), "v"(p2), "v"(p3) : "memory");
      if (!ok0 && x0.x == tag && x0.z == tag){ ok0=true; pay[0]=x0.y; pay[1]=x0.w; }
      if (!ok1 && x1.x == tag && x1.z == tag){ ok1=true; pay[2]=x1.y; pay[3]=x1.w; }
      if (!ok2 && x2.x == tag && x2.z == tag){ ok2=true; pay[4]=x2.y; pay[5]=x2.w; }
      if (!ok3 && x3.x == tag && x3.z == tag){ ok3=true; pay[6]=x3.y; pay[7]=x3.w; }
      if (ok0 & ok1 & ok2 & ok3) break;
    }
    if (!(ok0 & ok1 & ok2 & ok3) && count){
      if (++fails >= FAIL_STICKY) use_agent = true;
    }
  }
#pragma unroll
  for (int i = 0; i < 4; i++){
    bool ok = (i==0) ? ok0 : (i==1) ? ok1 : (i==2) ? ok2 : ok3;
    if (!ok){
      const u64* q = mb + l*2 + i*128;
      u64 a, c;
      do { a = aload64(q);   } while ((u32)a != tag);
      do { c = aload64(q+1); } while ((u32)c != tag);
      pay[2*i] = (u32)(a >> 32); pay[2*i+1] = (u32)(c >> 32);
    }
  }
#pragma unroll
  for (int i = 0; i < 4; i++){
    int k0 = l*2 + i*128;
    int ad = k0 + 2*(k0 >> SHIFT);
    float2 f { __uint_as_float(pay[2*i]), __uint_as_float(pay[2*i+1]) };
    *(float2*)&stgp[ad] = f;
  }
}

// ---------------- biwc = b_iw + input_b --------------------------------------
__global__ __launch_bounds__(256) void biwc_k(const float* __restrict__ b_iw,
                                              const float* __restrict__ input_b,
                                              float* __restrict__ biwc)
{
  int i = blockIdx.x*256 + threadIdx.x;
  if (i < HID) biwc[i] = b_iw[i] + input_b[i];
}

// ---------------- generic fp32 GEMM: C = A(MxK) @ W(KxN) + bias (opt gelu) --
template<bool GELU>
__global__ __launch_bounds__(256) void gemm_k(
    const float* __restrict__ A, const float* __restrict__ W,
    const float* __restrict__ bias, float* __restrict__ C,
    int M, int N, int K)
{
  __shared__ float As[16][68];
  __shared__ float Ws[16][68];
  const int tid = threadIdx.x;
  const int mb = blockIdx.y*64, nb = blockIdx.x*64;
  const int tx = tid & 15, ty = tid >> 4;
  const int am = tid >> 2, ak = (tid & 3)*4;
  const int wk = tid >> 4, wn = (tid & 15)*4;
  float acc[4][4] = {};
  const float* Aptr = A + (size_t)(mb+am)*K + ak;
  for (int kt = 0; kt < K; kt += 16){
    float4 av = *(const float4*)(Aptr + kt);
    float4 wv = *(const float4*)(W + (size_t)(kt+wk)*N + nb + wn);
    As[ak  ][am] = av.x; As[ak+1][am] = av.y; As[ak+2][am] = av.z; As[ak+3][am] = av.w;
    *(float4*)&Ws[wk][wn] = wv;
    __syncthreads();
#pragma unroll
    for (int kk = 0; kk < 16; kk++){
      float4 a4 = *(const float4*)&As[kk][ty*4];
      float4 w4 = *(const float4*)&Ws[kk][tx*4];
      float ar[4] = {a4.x, a4.y, a4.z, a4.w};
      float wr[4] = {w4.x, w4.y, w4.z, w4.w};
#pragma unroll
      for (int i = 0; i < 4; i++)
#pragma unroll
        for (int j = 0; j < 4; j++)
          acc[i][j] = fmaf(ar[i], wr[j], acc[i][j]);
    }
    __syncthreads();
  }
#pragma unroll
  for (int i = 0; i < 4; i++){
    int row = mb + ty*4 + i;
    float o[4];
#pragma unroll
    for (int j = 0; j < 4; j++){
      float v = acc[i][j] + bias[nb + tx*4 + j];
      o[j] = GELU ? gelu_f(v) : v;
    }
    float4 o4 = {o[0], o[1], o[2], o[3]};
    *(float4*)(C + (size_t)row*N + nb + tx*4) = o4;
  }
}

// ---------------- sequential h-recurrence: wave-complete, 1 bar/step ---------
// ctl[0..3]=claim counters, ctl[4]=nclaimed, ctl[8..11]=ready counters
__global__ __launch_bounds__(256, 1) void scan_k(
    const float* __restrict__ w_ff1, const float* __restrict__ w_rw,
    const float* __restrict__ w_ff2,
    const float* __restrict__ w_ta, const float* __restrict__ w_tb,
    const float* __restrict__ bff2, const float* __restrict__ b_ta,
    const float* __restrict__ b_tb, const float* __restrict__ rb,
    const float* __restrict__ PRE, const float* __restrict__ INPC,
    float* __restrict__ Hout,
    u64* __restrict__ exh, u64* __restrict__ exf1, u64* __restrict__ exf2,
    u64* __restrict__ fexh, u64* __restrict__ fexf1, u64* __restrict__ fexf2,
    int* __restrict__ ctl)
{
  // transposed panels: lane-consecutive float2 reads (R5's zero-conflict pattern)
  __shared__ float WA[16384];     // [w][j:32][lane:64] f2   64 KB
  __shared__ float WB[8192];      // [w][j:16][lane:64] f2   32 KB
  __shared__ float WC[8192];      //                          32 KB
  __shared__ float stg[4*544];    // per-wave staging (padded)
  __shared__ float pre_lds[16*16], ic_lds[16*16];   // 16-step input chunks
  __shared__ float rec_loc[2*16]; // t&1 double-buffered
  __shared__ int sh_chain, sh_sub;

  const int tid = threadIdx.x;

  // ---- dynamic chain/slot claim on the block's MEASURED XCD ----
  if (tid == 0){
    u32 xcc;
    asm volatile("s_getreg_b32 %0, hwreg(HW_REG_XCC_ID)" : "=s"(xcc));
    int xcd = (int)(xcc & 7);
    int chain = -1, sub = -1;
    if (xcd < BB){
      int s = __hip_atomic_fetch_add(&ctl[xcd], 1, __ATOMIC_RELAXED, __HIP_MEMORY_SCOPE_AGENT);
      if (s < 32){ chain = xcd; sub = s;
        __hip_atomic_fetch_add(&ctl[4], 1, __ATOMIC_RELAXED, __HIP_MEMORY_SCOPE_AGENT); }
    }
    if (chain < 0){
      for (int spin = 0; spin < 8000; ++spin){
        if (aloadi(&ctl[4]) >= BB*32) break;
        __builtin_amdgcn_s_sleep(2);
      }
      if (aloadi(&ctl[4]) < BB*32){
        for (int c = 0; c < BB && chain < 0; c++){
          int s = __hip_atomic_fetch_add(&ctl[c], 1, __ATOMIC_RELAXED, __HIP_MEMORY_SCOPE_AGENT);
          if (s < 32){ chain = c; sub = s;
            __hip_atomic_fetch_add(&ctl[4], 1, __ATOMIC_RELAXED, __HIP_MEMORY_SCOPE_AGENT); }
        }
      }
    }
    sh_chain = chain; sh_sub = sub;
  }
  __syncthreads();
  const int b = sh_chain, sub = sh_sub;
  if (b < 0) return;
  const int col0 = sub*16;

  u64* exh_b   = exh   + b*512;
  u64* exf1_b  = exf1  + b*512;
  u64* exf2_b  = exf2  + b*512;
  u64* fexh_b  = fexh  + b*512;
  u64* fexf1_b = fexf1 + b*512;
  u64* fexf2_b = fexf2 + b*512;

  // publish initial h (tag 0) via local L2 (mirror zeroed by memset = tag 0)
  if (tid < 16) fstore64(&fexh_b[col0 + tid], packtag(0.f, 0u));

  // ---- fill weight panels (coalesced over cols) ----
  // WA: o in 0..31 (o<16: ff1 h-part; else w_rw), float addr:
  //   ((w*32 + j)*64 + kp*8 + ow)*2 + e   with w=o>>3,ow=o&7,kp=k>>6,j=(k&63)>>1,e=k&1
  for (int idx = tid; idx < 32*512; idx += 256){
    int k = idx >> 5, o = idx & 31;
    float v = (o < 16) ? w_ff1[(size_t)(512+k)*HID + col0 + o]
                       : w_rw [(size_t)k*HID + col0 + o - 16];
    int fa = ((((o>>3)*32 + ((k&63)>>1))*64) + (k>>6)*8 + (o&7))*2 + (k&1);
    WA[fa] = v;
  }
  // WB/WC: c in 0..15, addr ((w*16+j)*64 + kp*4 + cw)*2+e, w=c>>2,cw=c&3,kp=k>>5
  for (int idx = tid; idx < 16*512; idx += 256){
    int k = idx >> 4, c = idx & 15;
    int fa = ((((c>>2)*16 + ((k&31)>>1))*64) + (k>>5)*4 + (c&3))*2 + (k&1);
    WB[fa] = w_ff2[(size_t)k*HID + col0 + c];
    WC[fa] = w_ta[(size_t)k*HID + col0 + c] + w_tb[(size_t)k*HID + col0 + c];
  }
  // ---- prologue input chunk: steps 0..15 ----
  for (int i = tid; i < 512; i += 256){
    int arr = i >> 8, s = (i >> 4) & 15, c = i & 15;
    float v = (arr ? INPC : PRE)[((size_t)b*SS + s)*HID + col0 + c];
    if (arr) ic_lds[s*16 + c] = v; else pre_lds[s*16 + c] = v;
  }
  const int w = tid >> 6, l = tid & 63;
  float* stgw = stg + w*544;
  const int cT = w*4 + (l & 3);                    // B/C out (0..15)
  const int oT = w*8 + (l & 7);                    // A out (0..31)
  const int khT = col0 + cT;                       // GLOBAL h index (R9 bugfix)
  const int khAd = khT + 2*(khT >> 6);             // padded staging addr
  const float bff2v = bff2[col0 + cT];
  const float b3v   = b_ta[col0 + cT] + b_tb[col0 + cT];
  const float rbv   = (w >= 2) ? rb[col0 + (w-2)*8 + (l & 7)] : 0.f;
  __syncthreads();

  // ---- chain-wide ready barrier ----
  if (tid == 0){
    __hip_atomic_fetch_add(&ctl[8 + b], 1, __ATOMIC_RELEASE, __HIP_MEMORY_SCOPE_AGENT);
    while (__hip_atomic_load(&ctl[8 + b], __ATOMIC_ACQUIRE, __HIP_MEMORY_SCOPE_AGENT) < 32)
      __builtin_amdgcn_s_sleep(1);
  }
  __syncthreads();

  int fails = 0; bool use_agent = false;

  for (int t = 0; t < SS; t++){
    const bool cnt = (t >= WARMUP_T);
    // refill issue (8-ahead, 16-slot double-buffer)
    const bool refill = ((t & 7) == 7) && (t >= 15) && (t + 8 < SS);
    float rfv = 0.f; int rf_slot = 0, rf_c = 0, rf_arr = 0;
    if (refill){
      rf_arr = tid >> 7; int s = (tid >> 4) & 7; rf_c = tid & 15;
      rf_slot = (t + 1 + s) & 15;
      rfv = (rf_arr ? INPC : PRE)[((size_t)b*SS + (t+1+s))*HID + col0 + rf_c];
    }
    // ======== stage A (wave-complete) ========
    pollw<6>(fexh_b, exh_b, (u32)t, stgw, l, fails, use_agent, cnt);
    float h_own = stgw[khAd];                       // own old-h (global col)
    {
      const float2* wp = (const float2*)WA + w*2048 + l;
      const float2* hp = (const float2*)stgw + (l>>3)*33;
      float a0=0.f, a1=0.f, a2=0.f, a3=0.f;
#pragma unroll
      for (int j = 0; j < 32; j += 2){
        float2 w0 = wp[j*64],     h0 = hp[j];
        float2 w1 = wp[(j+1)*64], h1 = hp[j+1];
        a0 = fmaf(w0.x, h0.x, a0); a1 = fmaf(w0.y, h0.y, a1);
        a2 = fmaf(w1.x, h1.x, a2); a3 = fmaf(w1.y, h1.y, a3);
      }
      float s = (a0+a1)+(a2+a3);
      s += __shfl_xor(s, 8); s += __shfl_xor(s, 16); s += __shfl_xor(s, 32);
      if (l < 8){
        if (w < 2){
          float v = gelu_f(pre_lds[(t & 15)*16 + oT] + s);
          u64 pk = packtag(v, (u32)(t+1));
          fstore64(&fexf1_b[col0 + oT], pk);
          astore64(&exf1_b[col0 + oT], pk);
        } else {
          rec_loc[(t & 1)*16 + (w-2)*8 + l] = gelu_f(s + rbv);
        }
      }
    }
    if (refill){
      if (rf_arr) ic_lds[rf_slot*16 + rf_c] = rfv;
      else        pre_lds[rf_slot*16 + rf_c] = rfv;
    }
    __syncthreads();                                // THE one bar per step
    // ======== stage B ========
    pollw<5>(fexf1_b, exf1_b, (u32)(t+1), stgw, l, fails, use_agent, cnt);
    {
      const float2* wp = (const float2*)WB + w*1024 + l;
      const float2* fp = (const float2*)stgw + (l>>2)*17;
      float a0=0.f, a1=0.f, a2=0.f, a3=0.f;
#pragma unroll
      for (int j = 0; j < 16; j += 2){
        float2 w0 = wp[j*64],     f0 = fp[j];
        float2 w1 = wp[(j+1)*64], f1 = fp[j+1];
        a0 = fmaf(w0.x, f0.x, a0); a1 = fmaf(w0.y, f0.y, a1);
        a2 = fmaf(w1.x, f1.x, a2); a3 = fmaf(w1.y, f1.y, a3);
      }
      float s = (a0+a1)+(a2+a3);
      s += __shfl_xor(s, 4); s += __shfl_xor(s, 8);
      s += __shfl_xor(s, 16); s += __shfl_xor(s, 32);
      if (l < 4){
        float v = gelu_f(s + bff2v);
        u64 pk = packtag(v, (u32)(t+1));
        fstore64(&fexf2_b[col0 + cT], pk);
        astore64(&exf2_b[col0 + cT], pk);
      }
    }
    // ======== stage C ========
    pollw<5>(fexf2_b, exf2_b, (u32)(t+1), stgw, l, fails, use_agent, cnt);
    {
      const float2* wp = (const float2*)WC + w*1024 + l;
      const float2* fp = (const float2*)stgw + (l>>2)*17;
      float a0=0.f, a1=0.f, a2=0.f, a3=0.f;
#pragma unroll
      for (int j = 0; j < 16; j += 2){
        float2 w0 = wp[j*64],     f0 = fp[j];
        float2 w1 = wp[(j+1)*64], f1 = fp[j+1];
        a0 = fmaf(w0.x, f0.x, a0); a1 = fmaf(w0.y, f0.y, a1);
        a2 = fmaf(w1.x, f1.x, a2); a3 = fmaf(w1.y, f1.y, a3);
      }
      float s = (a0+a1)+(a2+a3);
      s += __shfl_xor(s, 4); s += __shfl_xor(s, 8);
      s += __shfl_xor(s, 16); s += __shfl_xor(s, 32);
      if (l < 4){
        float ti = 1.0f / (1.0f + expf(-(s + b3v)));
        float nh = h_own*(1.0f - ti)
                 + ti*(ic_lds[(t & 15)*16 + cT] + rec_loc[(t & 1)*16 + cT]);
        u64 pk = packtag(nh, (u32)(t+1));
        fstore64(&fexh_b[col0 + cT], pk);
        astore64(&exh_b[col0 + cT], pk);
        Hout[((size_t)b*SS + t)*HID + col0 + cT] = nh;
      }
    }
  }

  // ---- chain-wide done-barrier (mirror @ tag SS), then poison fast tags ----
  {
    const u64* q0 = exh_b + tid;
    const u64* q1 = exh_b + tid + 256;
    u64 a;
    do { a = aload64(q0); } while ((u32)a != (u32)SS);
    do { a = aload64(q1); } while ((u32)a != (u32)SS);
  }
  __syncthreads();
  for (int i = tid; i < 512; i += 256){
    fstore64(&fexh_b[i],  0xFFFFFFFFull);
    fstore64(&fexf1_b[i], 0xFFFFFFFFull);
    fstore64(&fexf2_b[i], 0xFFFFFFFFull);
  }
}

// ---------------- softmax over 128 experts ----------------------------------
__global__ __launch_bounds__(256) void softmax_k(const float* __restrict__ LOGITS,
                                                 float* __restrict__ SM)
{
  int wv = threadIdx.x >> 6, lane = threadIdx.x & 63;
  int row = blockIdx.x*4 + wv;
  const float* xp = LOGITS + (size_t)row*NEXP;
  float x0 = xp[lane], x1 = xp[lane+64];
  float m = fmaxf(x0, x1);
#pragma unroll
  for (int d = 1; d < 64; d <<= 1) m = fmaxf(m, __shfl_xor(m, d));
  float e0 = expf(x0 - m), e1 = expf(x1 - m);
  float s = e0 + e1;
#pragma unroll
  for (int d = 1; d < 64; d <<= 1) s += __shfl_xor(s, d);
  float inv = 1.0f / s;
  float* op = SM + (size_t)row*NEXP;
  op[lane] = e0*inv; op[lane+64] = e1*inv;
}

// ---------------- smoothing (20-term window == exact recurrence) + top2 -----
__global__ __launch_bounds__(256) void smooth_topk_k(const float* __restrict__ SM,
                                                     float* __restrict__ out)
{
  int wv = threadIdx.x >> 6, lane = threadIdx.x & 63;
  int row = blockIdx.x*4 + wv;
  int b = row >> 11, t = row & 2047;
  const float* base = SM + (size_t)row*NEXP;
  float a0 = 0.f, a1 = 0.f;
  float coef = 0.9f;
  int nt = t < 20 ? t : 20;
  for (int j = 0; j < nt; j++){
    const float* pj = base - j*NEXP;
    a0 += coef * pj[lane];
    a1 += coef * pj[lane+64];
    coef *= 0.1f;
  }
  if (t < 20){
    const float* s0 = SM + (size_t)b*SS*NEXP;
    float c0 = coef * (1.0f/0.9f);    // 0.1^t
    a0 += c0 * s0[lane];
    a1 += c0 * s0[lane+64];
  }
  float v0, v1; int i0, i1;
  if (a0 >= a1){ v0=a0; i0=lane;    v1=a1; i1=lane+64; }
  else         { v0=a1; i0=lane+64; v1=a0; i1=lane;    }
#pragma unroll
  for (int d = 1; d < 64; d <<= 1){
    float ov0 = __shfl_xor(v0, d), ov1 = __shfl_xor(v1, d);
    int   oi0 = __shfl_xor(i0, d), oi1 = __shfl_xor(i1, d);
    bool firstMine = (v0 > ov0) || (v0 == ov0 && i0 < oi0);
    float nv0, nv1; int ni0, ni1;
    if (firstMine){
      nv0 = v0; ni0 = i0;
      bool s = (v1 > ov0) || (v1 == ov0 && i1 < oi0);
      nv1 = s ? v1 : ov0; ni1 = s ? i1 : oi0;
    } else {
      nv0 = ov0; ni0 = oi0;
      bool s = (ov1 > v0) || (ov1 == v0 && oi1 < i0);
      nv1 = s ? ov1 : v0; ni1 = s ? oi1 : i0;
    }
    v0 = nv0; v1 = nv1; i0 = ni0; i1 = ni1;
  }
  if (lane == 0){
    float ssum = v0 + v1;
    size_t o = (size_t)row*2;
    out[o]     = (float)i0;
    out[o+1]   = (float)i1;
    out[16384 + o]   = v0 / ssum;
    out[16384 + o+1] = v1 / ssum;
  }
}

// ---------------- host launch ------------------------------------------------
extern "C" void kernel_launch(void* const* d_in, const int* in_sizes, int n_in,
                              void* d_out, int out_size, void* d_ws, size_t ws_size,
                              hipStream_t stream)
{
  (void)in_sizes; (void)n_in; (void)out_size;
  const float* x       = (const float*)d_in[0];
  const float* w_in    = (const float*)d_in[1];
  const float* b_in    = (const float*)d_in[2];
  const float* w_ff1   = (const float*)d_in[3];
  const float* b_ff1   = (const float*)d_in[4];
  const float* w_ff2   = (const float*)d_in[5];
  const float* b_ff2   = (const float*)d_in[6];
  const float* w_ta    = (const float*)d_in[7];
  const float* b_ta    = (const float*)d_in[8];
  const float* w_tb    = (const float*)d_in[9];
  const float* b_tb    = (const float*)d_in[10];
  const float* w_iw    = (const float*)d_in[11];
  const float* b_iw    = (const float*)d_in[12];
  const float* input_b = (const float*)d_in[13];
  const float* w_rw    = (const float*)d_in[14];
  const float* r_b     = (const float*)d_in[15];
  const float* w_g1    = (const float*)d_in[16];
  const float* b_g1    = (const float*)d_in[17];
  const float* w_g2    = (const float*)d_in[18];
  const float* b_g2    = (const float*)d_in[19];

  float* ws    = (float*)d_ws;
  float* XT    = ws + 0;               // 8192*512
  float* PRE   = ws + 4194304;         // 8192*512
  float* INPC  = ws + 8388608;         // 8192*512
  float* Hbuf  = ws + 12582912;        // 8192*512
  float* G1    = ws + 0;               // reuse XT+PRE after scan (8192*1024)
  float* LOGB  = ws + 8388608;         // reuse INPC (8192*128)
  float* SM    = ws + 9437184;         // 8192*128
  float* biwc  = ws + 16777216;        // 512
  u64*   exh   = (u64*)(ws + 16777728);// mirrors: 4*512 u64 each
  u64*   exf1  = (u64*)(ws + 16781824);
  u64*   exf2  = (u64*)(ws + 16785920);
  u64*   fexh  = (u64*)(ws + 16790016);// fast: 4*512 u64 each
  u64*   fexf1 = (u64*)(ws + 16794112);
  u64*   fexf2 = (u64*)(ws + 16798208);
  int*   ctl   = (int*)(ws + 16802304);// claim[4], nclaimed, pad, ready[4]
  if (ws_size < (size_t)16802368 * sizeof(float)) return;

  // reset mirror tags + claim/ready control (fast buffers self-poisoning)
  hipMemsetAsync(ws + 16777728, 0, 3 * 2048 * sizeof(u64), stream);
  hipMemsetAsync(ctl, 0, 16 * sizeof(int), stream);

  biwc_k<<<2, 256, 0, stream>>>(b_iw, input_b, biwc);
  gemm_k<false><<<dim3(8, 128), 256, 0, stream>>>(x, w_in, b_in, XT, NROW, 512, 4096);
  gemm_k<false><<<dim3(8, 128), 256, 0, stream>>>(XT, w_ff1, b_ff1, PRE, NROW, 512, 512);
  gemm_k<true ><<<dim3(8, 128), 256, 0, stream>>>(XT, w_iw, biwc, INPC, NROW, 512, 512);
  scan_k<<<2048, 256, 0, stream>>>(w_ff1, w_rw, w_ff2, w_ta, w_tb,
                                   b_ff2, b_ta, b_tb, r_b,
                                   PRE, INPC, Hbuf, exh, exf1, exf2,
                                   fexh, fexf1, fexf2, ctl);
  gemm_k<true ><<<dim3(16, 128), 256, 0, stream>>>(Hbuf, w_g1, b_g1, G1, NROW, 1024, 512);
  gemm_k<false><<<dim3(2, 128), 256, 0, stream>>>(G1, w_g2, b_g2, LOGB, NROW, 128, 1024);
  softmax_k<<<2048, 256, 0, stream>>>(LOGB, SM);
  smooth_topk_k<<<2048, 256, 0, stream>>>(SM, (float*)d_out);
}

// Round 11
// 10997.846 us; speedup vs baseline: 2.1769x; 2.1769x over previous
//
#include <hip/hip_runtime.h>
#include <cmath>

#define HID 512
#define NEXP 128
#define BB 4
#define SS 2048
#define NROW (BB*SS)      // 8192
#define FAST_ITERS 96
#define FAIL_STICKY 16
#define WARMUP_T 16

typedef unsigned long long u64;
typedef unsigned int u32;
typedef unsigned int v4u __attribute__((ext_vector_type(4)));

__device__ __forceinline__ float gelu_f(float x){
  return 0.5f*x*(1.0f + erff(x*0.70710678118654752440f));
}

__device__ __forceinline__ u64 aload64(const u64* p){
  return __hip_atomic_load(p, __ATOMIC_RELAXED, __HIP_MEMORY_SCOPE_AGENT);
}
__device__ __forceinline__ void astore64(u64* p, u64 v){
  __hip_atomic_store(p, v, __ATOMIC_RELAXED, __HIP_MEMORY_SCOPE_AGENT);
}
__device__ __forceinline__ int aloadi(const int* p){
  return __hip_atomic_load(p, __ATOMIC_RELAXED, __HIP_MEMORY_SCOPE_AGENT);
}
__device__ __forceinline__ void fstore64(u64* p, u64 v){
  asm volatile("global_store_dwordx2 %0, %1, off" :: "v"(p), "v"(v) : "memory");
}
__device__ __forceinline__ u64 packtag(float f, u32 tag){
  return ((u64)__float_as_uint(f) << 32) | (u64)tag;
}

// per-wave quarter poll: wave w, lane l polls u64 words {w*128+2l, +1} (its
// own k-quarter). ONE dwordx4 sc0 per lane per iteration. Mirror fallback.
// Deposit to this wave's padded LDS region:
//   stage A: entry = w*68 + (l>>5)*33 + (l&31)   (pAl pad 33)
//   stage B/C: entry = w*68 + (l>>4)*17 + (l&15) (pBl pad 17)
template<bool STAGE_A>
__device__ __forceinline__ void pollq(const u64* fb, const u64* mb, u32 tag,
                                      float* stg, int w, int l,
                                      int& fails, bool& use_agent, bool count){
  const u64* p = fb + w*128 + l*2;
  u32 pay0 = 0, pay1 = 0;
  bool ok = false;
  if (!use_agent){
    for (int it = 0; it < FAST_ITERS; ++it){
      v4u x;
      asm volatile("global_load_dwordx4 %0, %1, off sc0\n\ts_waitcnt vmcnt(0)"
                   : "=&v"(x) : "v"(p) : "memory");
      if (x.x == tag && x.z == tag){ ok = true; pay0 = x.y; pay1 = x.w; break; }
    }
    if (!ok && count){
      if (++fails >= FAIL_STICKY) use_agent = true;
    }
  }
  if (!ok){
    const u64* q = mb + w*128 + l*2;
    u64 a, c;
    do { a = aload64(q);   } while ((u32)a != tag);
    do { c = aload64(q+1); } while ((u32)c != tag);
    pay0 = (u32)(a >> 32); pay1 = (u32)(c >> 32);
  }
  int e = STAGE_A ? (w*68 + (l>>5)*33 + (l&31))
                  : (w*68 + (l>>4)*17 + (l&15));
  float2 f = { __uint_as_float(pay0), __uint_as_float(pay1) };
  *(float2*)&stg[e*2] = f;
}

// ---------------- biwc = b_iw + input_b --------------------------------------
__global__ __launch_bounds__(256) void biwc_k(const float* __restrict__ b_iw,
                                              const float* __restrict__ input_b,
                                              float* __restrict__ biwc)
{
  int i = blockIdx.x*256 + threadIdx.x;
  if (i < HID) biwc[i] = b_iw[i] + input_b[i];
}

// ---------------- generic fp32 GEMM: C = A(MxK) @ W(KxN) + bias (opt gelu) --
template<bool GELU>
__global__ __launch_bounds__(256) void gemm_k(
    const float* __restrict__ A, const float* __restrict__ W,
    const float* __restrict__ bias, float* __restrict__ C,
    int M, int N, int K)
{
  __shared__ float As[16][68];
  __shared__ float Ws[16][68];
  const int tid = threadIdx.x;
  const int mb = blockIdx.y*64, nb = blockIdx.x*64;
  const int tx = tid & 15, ty = tid >> 4;
  const int am = tid >> 2, ak = (tid & 3)*4;
  const int wk = tid >> 4, wn = (tid & 15)*4;
  float acc[4][4] = {};
  const float* Aptr = A + (size_t)(mb+am)*K + ak;
  for (int kt = 0; kt < K; kt += 16){
    float4 av = *(const float4*)(Aptr + kt);
    float4 wv = *(const float4*)(W + (size_t)(kt+wk)*N + nb + wn);
    As[ak  ][am] = av.x; As[ak+1][am] = av.y; As[ak+2][am] = av.z; As[ak+3][am] = av.w;
    *(float4*)&Ws[wk][wn] = wv;
    __syncthreads();
#pragma unroll
    for (int kk = 0; kk < 16; kk++){
      float4 a4 = *(const float4*)&As[kk][ty*4];
      float4 w4 = *(const float4*)&Ws[kk][tx*4];
      float ar[4] = {a4.x, a4.y, a4.z, a4.w};
      float wr[4] = {w4.x, w4.y, w4.z, w4.w};
#pragma unroll
      for (int i = 0; i < 4; i++)
#pragma unroll
        for (int j = 0; j < 4; j++)
          acc[i][j] = fmaf(ar[i], wr[j], acc[i][j]);
    }
    __syncthreads();
  }
#pragma unroll
  for (int i = 0; i < 4; i++){
    int row = mb + ty*4 + i;
    float o[4];
#pragma unroll
    for (int j = 0; j < 4; j++){
      float v = acc[i][j] + bias[nb + tx*4 + j];
      o[j] = GELU ? gelu_f(v) : v;
    }
    float4 o4 = {o[0], o[1], o[2], o[3]};
    *(float4*)(C + (size_t)row*N + nb + tx*4) = o4;
  }
}

// ---------------- sequential h-recurrence: wave-quartered, 3 bars/step -------
// Wave w owns k-quarter [128w,128w+128) of every incoming vector.
// Thread mapping: stage A: (pAl=l>>5, cA=l&31), k=[128w+pAl*64, +64)
//                 stage B/C: (pBl=l>>4, cB=l&15), k=[128w+pBl*32, +32)
// Final sums: wave1->ff1/rec, wave2->ff2, wave3->h (h_reg in registers).
// ctl[0..3]=claim counters, ctl[4]=nclaimed, ctl[8..11]=ready counters
__global__ __launch_bounds__(256, 1) void scan_k(
    const float* __restrict__ w_ff1, const float* __restrict__ w_rw,
    const float* __restrict__ w_ff2,
    const float* __restrict__ w_ta, const float* __restrict__ w_tb,
    const float* __restrict__ bff2, const float* __restrict__ b_ta,
    const float* __restrict__ b_tb, const float* __restrict__ rb,
    const float* __restrict__ PRE, const float* __restrict__ INPC,
    float* __restrict__ Hout,
    u64* __restrict__ exh, u64* __restrict__ exf1, u64* __restrict__ exf2,
    u64* __restrict__ fexh, u64* __restrict__ fexf1, u64* __restrict__ fexf2,
    int* __restrict__ ctl)
{
  __shared__ float WA[16384];   // 64KB [w][pAl][j:32][cA:32] float2
  __shared__ float WB[8192];    // 32KB [w][pBl][j:16][cB:16] float2
  __shared__ float WC[8192];    // 32KB
  __shared__ float stgA[544], stgB[544], stgC[544];  // 4 regions x 68 f2
  __shared__ float pre_lds[256], ic_lds[256];        // 16-step chunks
  __shared__ float redA[128], redB[64], redC[64];
  __shared__ float rec_loc[16];
  __shared__ int sh_chain, sh_sub;

  const int tid = threadIdx.x;

  // ---- dynamic chain/slot claim on the block's MEASURED XCD ----
  if (tid == 0){
    u32 xcc;
    asm volatile("s_getreg_b32 %0, hwreg(HW_REG_XCC_ID)" : "=s"(xcc));
    int xcd = (int)(xcc & 7);
    int chain = -1, sub = -1;
    if (xcd < BB){
      int s = __hip_atomic_fetch_add(&ctl[xcd], 1, __ATOMIC_RELAXED, __HIP_MEMORY_SCOPE_AGENT);
      if (s < 32){ chain = xcd; sub = s;
        __hip_atomic_fetch_add(&ctl[4], 1, __ATOMIC_RELAXED, __HIP_MEMORY_SCOPE_AGENT); }
    }
    if (chain < 0){
      for (int spin = 0; spin < 8000; ++spin){
        if (aloadi(&ctl[4]) >= BB*32) break;
        __builtin_amdgcn_s_sleep(2);
      }
      if (aloadi(&ctl[4]) < BB*32){
        for (int c = 0; c < BB && chain < 0; c++){
          int s = __hip_atomic_fetch_add(&ctl[c], 1, __ATOMIC_RELAXED, __HIP_MEMORY_SCOPE_AGENT);
          if (s < 32){ chain = c; sub = s;
            __hip_atomic_fetch_add(&ctl[4], 1, __ATOMIC_RELAXED, __HIP_MEMORY_SCOPE_AGENT); }
        }
      }
    }
    sh_chain = chain; sh_sub = sub;
  }
  __syncthreads();
  const int b = sh_chain, sub = sh_sub;
  if (b < 0) return;
  const int col0 = sub*16;

  u64* exh_b   = exh   + b*512;
  u64* exf1_b  = exf1  + b*512;
  u64* exf2_b  = exf2  + b*512;
  u64* fexh_b  = fexh  + b*512;
  u64* fexf1_b = fexf1 + b*512;
  u64* fexf2_b = fexf2 + b*512;

  // publish initial h (tag 0) via local L2 (mirror zeroed by memset = tag 0)
  if (tid < 16) fstore64(&fexh_b[col0 + tid], packtag(0.f, 0u));

  // ---- fill weight panels ----
  // WA entry = (k>>7)*2048 + ((k>>6)&1)*1024 + ((k&63)>>1)*32 + cA, elem k&1
  for (int idx = tid; idx < 32*512; idx += 256){
    int k = idx >> 5, cA = idx & 31;
    float v = (cA < 16) ? w_ff1[(size_t)(512+k)*HID + col0 + cA]
                        : w_rw [(size_t)k*HID + col0 + cA - 16];
    int e = (k>>7)*2048 + ((k>>6)&1)*1024 + ((k&63)>>1)*32 + cA;
    WA[e*2 + (k&1)] = v;
  }
  // WB/WC entry = (k>>7)*1024 + ((k>>5)&3)*256 + ((k&31)>>1)*16 + cB
  for (int idx = tid; idx < 16*512; idx += 256){
    int k = idx >> 4, cB = idx & 15;
    int e = (k>>7)*1024 + ((k>>5)&3)*256 + ((k&31)>>1)*16 + cB;
    WB[e*2 + (k&1)] = w_ff2[(size_t)k*HID + col0 + cB];
    WC[e*2 + (k&1)] = w_ta[(size_t)k*HID + col0 + cB]
                    + w_tb[(size_t)k*HID + col0 + cB];
  }
  // ---- prologue PRE/INPC chunk (steps 0..15) ----
  for (int i = tid; i < 512; i += 256){
    int arr = i >> 8, s = (i >> 4) & 15, c = i & 15;
    float v = (arr ? INPC : PRE)[((size_t)b*SS + s)*HID + col0 + c];
    if (arr) ic_lds[s*16 + c] = v; else pre_lds[s*16 + c] = v;
  }
  const int w = tid >> 6, l = tid & 63;
  const int cA = l & 31, pAl = l >> 5;
  const int cB = l & 15, pBl = l >> 4;
  const float rbv   = (w == 1 && l >= 16 && l < 32) ? rb[col0 + l - 16] : 0.f;
  const float bff2v = (w == 2 && l < 16) ? bff2[col0 + l] : 0.f;
  const float b3v   = (w == 3 && l < 16) ? (b_ta[col0+l] + b_tb[col0+l]) : 0.f;
  float h_reg = 0.f;   // live in wave 3 lanes 0-15
  __syncthreads();

  // ---- chain-wide ready barrier ----
  if (tid == 0){
    __hip_atomic_fetch_add(&ctl[8 + b], 1, __ATOMIC_RELEASE, __HIP_MEMORY_SCOPE_AGENT);
    while (__hip_atomic_load(&ctl[8 + b], __ATOMIC_ACQUIRE, __HIP_MEMORY_SCOPE_AGENT) < 32)
      __builtin_amdgcn_s_sleep(1);
  }
  __syncthreads();

  const float2* wa = (const float2*)WA + w*2048 + pAl*1024 + cA;  // +j*32
  const float2* ha = (const float2*)stgA + w*68 + pAl*33;         // +j
  const float2* wb = (const float2*)WB + w*1024 + pBl*256 + cB;   // +j*16
  const float2* hb = (const float2*)stgB + w*68 + pBl*17;         // +j
  const float2* wc = (const float2*)WC + w*1024 + pBl*256 + cB;
  const float2* hc = (const float2*)stgC + w*68 + pBl*17;

  int fails = 0; bool use_agent = false;

  for (int t = 0; t < SS; t++){
    const bool cnt = (t >= WARMUP_T);
    // ======== stage A: poll own quarter of h, partial matvec, redA ========
    pollq<true>(fexh_b, exh_b, (u32)t, stgA, w, l, fails, use_agent, cnt);
    {
      float a0=0.f, a1=0.f, a2=0.f, a3=0.f;
#pragma unroll
      for (int j = 0; j < 32; j += 2){
        float2 w0 = wa[j*32],     h0 = ha[j];
        float2 w1 = wa[(j+1)*32], h1 = ha[j+1];
        a0 = fmaf(w0.x, h0.x, a0); a1 = fmaf(w0.y, h0.y, a1);
        a2 = fmaf(w1.x, h1.x, a2); a3 = fmaf(w1.y, h1.y, a3);
      }
      float acc = (a0+a1)+(a2+a3);
      acc += __shfl_xor(acc, 32);          // combine pAl halves
      if (l < 32) redA[w*32 + l] = acc;
    }
    // refill issue (8-ahead into the 16-slot chunk), off critical path
    const bool refill = ((t & 7) == 7) && (t >= 15) && (t + 8 < SS);
    float rfv = 0.f; int rf_slot = 0, rf_c = 0, rf_arr = 0;
    if (refill){
      rf_arr = tid >> 7; int s = (tid >> 4) & 7; rf_c = tid & 15;
      rf_slot = (t + 1 + s) & 15;
      rfv = (rf_arr ? INPC : PRE)[((size_t)b*SS + (t+1+s))*HID + col0 + rf_c];
    }
    __syncthreads();                       // bar1
    // FS_A: wave 1 sums redA, publishes ff1 / writes rec_loc
    if (w == 1 && l < 32){
      float s = redA[l] + redA[32+l] + redA[64+l] + redA[96+l];
      if (l < 16){
        float v = gelu_f(pre_lds[(t & 15)*16 + l] + s);
        u64 pk = packtag(v, (u32)(t+1));
        fstore64(&fexf1_b[col0 + l], pk);
        astore64(&exf1_b[col0 + l], pk);
      } else {
        rec_loc[l - 16] = gelu_f(s + rbv);
      }
    }
    // ======== stage B ========
    pollq<false>(fexf1_b, exf1_b, (u32)(t+1), stgB, w, l, fails, use_agent, cnt);
    {
      float a0=0.f, a1=0.f, a2=0.f, a3=0.f;
#pragma unroll
      for (int j = 0; j < 16; j += 2){
        float2 w0 = wb[j*16],     f0 = hb[j];
        float2 w1 = wb[(j+1)*16], f1 = hb[j+1];
        a0 = fmaf(w0.x, f0.x, a0); a1 = fmaf(w0.y, f0.y, a1);
        a2 = fmaf(w1.x, f1.x, a2); a3 = fmaf(w1.y, f1.y, a3);
      }
      float acc = (a0+a1)+(a2+a3);
      acc += __shfl_xor(acc, 16);          // pBl pairs
      acc += __shfl_xor(acc, 32);
      if (l < 16) redB[w*16 + l] = acc;
    }
    if (refill){
      asm volatile("s_waitcnt vmcnt(0)" ::: "memory");
      if (rf_arr) ic_lds[rf_slot*16 + rf_c] = rfv;
      else        pre_lds[rf_slot*16 + rf_c] = rfv;
    }
    __syncthreads();                       // bar2
    // FS_B: wave 2 sums redB, publishes ff2
    if (w == 2 && l < 16){
      float s = redB[l] + redB[16+l] + redB[32+l] + redB[48+l];
      float v = gelu_f(s + bff2v);
      u64 pk = packtag(v, (u32)(t+1));
      fstore64(&fexf2_b[col0 + l], pk);
      astore64(&exf2_b[col0 + l], pk);
    }
    // ======== stage C ========
    pollq<false>(fexf2_b, exf2_b, (u32)(t+1), stgC, w, l, fails, use_agent, cnt);
    {
      float a0=0.f, a1=0.f, a2=0.f, a3=0.f;
#pragma unroll
      for (int j = 0; j < 16; j += 2){
        float2 w0 = wc[j*16],     f0 = hc[j];
        float2 w1 = wc[(j+1)*16], f1 = hc[j+1];
        a0 = fmaf(w0.x, f0.x, a0); a1 = fmaf(w0.y, f0.y, a1);
        a2 = fmaf(w1.x, f1.x, a2); a3 = fmaf(w1.y, f1.y, a3);
      }
      float acc = (a0+a1)+(a2+a3);
      acc += __shfl_xor(acc, 16);
      acc += __shfl_xor(acc, 32);
      if (l < 16) redC[w*16 + l] = acc;
    }
    __syncthreads();                       // bar3
    // FS_C: wave 3 sums redC, computes new h, publishes
    if (w == 3 && l < 16){
      float s = redC[l] + redC[16+l] + redC[32+l] + redC[48+l];
      float ti = 1.0f / (1.0f + expf(-(s + b3v)));
      float nh = h_reg*(1.0f - ti)
               + ti*(ic_lds[(t & 15)*16 + l] + rec_loc[l]);
      h_reg = nh;
      u64 pk = packtag(nh, (u32)(t+1));
      fstore64(&fexh_b[col0 + l], pk);
      astore64(&exh_b[col0 + l], pk);
      Hout[((size_t)b*SS + t)*HID + col0 + l] = nh;
    }
  }

  // ---- chain-wide done-barrier (mirror @ tag SS), then poison fast tags ----
  {
    const u64* q0 = exh_b + tid;
    const u64* q1 = exh_b + tid + 256;
    u64 a;
    do { a = aload64(q0); } while ((u32)a != (u32)SS);
    do { a = aload64(q1); } while ((u32)a != (u32)SS);
  }
  __syncthreads();
  for (int i = tid; i < 512; i += 256){
    fstore64(&fexh_b[i],  0xFFFFFFFFull);
    fstore64(&fexf1_b[i], 0xFFFFFFFFull);
    fstore64(&fexf2_b[i], 0xFFFFFFFFull);
  }
}

// ---------------- softmax over 128 experts ----------------------------------
__global__ __launch_bounds__(256) void softmax_k(const float* __restrict__ LOGITS,
                                                 float* __restrict__ SM)
{
  int wv = threadIdx.x >> 6, lane = threadIdx.x & 63;
  int row = blockIdx.x*4 + wv;
  const float* xp = LOGITS + (size_t)row*NEXP;
  float x0 = xp[lane], x1 = xp[lane+64];
  float m = fmaxf(x0, x1);
#pragma unroll
  for (int d = 1; d < 64; d <<= 1) m = fmaxf(m, __shfl_xor(m, d));
  float e0 = expf(x0 - m), e1 = expf(x1 - m);
  float s = e0 + e1;
#pragma unroll
  for (int d = 1; d < 64; d <<= 1) s += __shfl_xor(s, d);
  float inv = 1.0f / s;
  float* op = SM + (size_t)row*NEXP;
  op[lane] = e0*inv; op[lane+64] = e1*inv;
}

// ---------------- smoothing (20-term window == exact recurrence) + top2 -----
__global__ __launch_bounds__(256) void smooth_topk_k(const float* __restrict__ SM,
                                                     float* __restrict__ out)
{
  int wv = threadIdx.x >> 6, lane = threadIdx.x & 63;
  int row = blockIdx.x*4 + wv;
  int b = row >> 11, t = row & 2047;
  const float* base = SM + (size_t)row*NEXP;
  float a0 = 0.f, a1 = 0.f;
  float coef = 0.9f;
  int nt = t < 20 ? t : 20;
  for (int j = 0; j < nt; j++){
    const float* pj = base - j*NEXP;
    a0 += coef * pj[lane];
    a1 += coef * pj[lane+64];
    coef *= 0.1f;
  }
  if (t < 20){
    const float* s0 = SM + (size_t)b*SS*NEXP;
    float c0 = coef * (1.0f/0.9f);    // 0.1^t
    a0 += c0 * s0[lane];
    a1 += c0 * s0[lane+64];
  }
  float v0, v1; int i0, i1;
  if (a0 >= a1){ v0=a0; i0=lane;    v1=a1; i1=lane+64; }
  else         { v0=a1; i0=lane+64; v1=a0; i1=lane;    }
#pragma unroll
  for (int d = 1; d < 64; d <<= 1){
    float ov0 = __shfl_xor(v0, d), ov1 = __shfl_xor(v1, d);
    int   oi0 = __shfl_xor(i0, d), oi1 = __shfl_xor(i1, d);
    bool firstMine = (v0 > ov0) || (v0 == ov0 && i0 < oi0);
    float nv0, nv1; int ni0, ni1;
    if (firstMine){
      nv0 = v0; ni0 = i0;
      bool s = (v1 > ov0) || (v1 == ov0 && i1 < oi0);
      nv1 = s ? v1 : ov0; ni1 = s ? i1 : oi0;
    } else {
      nv0 = ov0; ni0 = oi0;
      bool s = (ov1 > v0) || (ov1 == v0 && oi1 < i0);
      nv1 = s ? ov1 : v0; ni1 = s ? oi1 : i0;
    }
    v0 = nv0; v1 = nv1; i0 = ni0; i1 = ni1;
  }
  if (lane == 0){
    float ssum = v0 + v1;
    size_t o = (size_t)row*2;
    out[o]     = (float)i0;
    out[o+1]   = (float)i1;
    out[16384 + o]   = v0 / ssum;
    out[16384 + o+1] = v1 / ssum;
  }
}

// ---------------- host launch ------------------------------------------------
extern "C" void kernel_launch(void* const* d_in, const int* in_sizes, int n_in,
                              void* d_out, int out_size, void* d_ws, size_t ws_size,
                              hipStream_t stream)
{
  (void)in_sizes; (void)n_in; (void)out_size;
  const float* x       = (const float*)d_in[0];
  const float* w_in    = (const float*)d_in[1];
  const float* b_in    = (const float*)d_in[2];
  const float* w_ff1   = (const float*)d_in[3];
  const float* b_ff1   = (const float*)d_in[4];
  const float* w_ff2   = (const float*)d_in[5];
  const float* b_ff2   = (const float*)d_in[6];
  const float* w_ta    = (const float*)d_in[7];
  const float* b_ta    = (const float*)d_in[8];
  const float* w_tb    = (const float*)d_in[9];
  const float* b_tb    = (const float*)d_in[10];
  const float* w_iw    = (const float*)d_in[11];
  const float* b_iw    = (const float*)d_in[12];
  const float* input_b = (const float*)d_in[13];
  const float* w_rw    = (const float*)d_in[14];
  const float* r_b     = (const float*)d_in[15];
  const float* w_g1    = (const float*)d_in[16];
  const float* b_g1    = (const float*)d_in[17];
  const float* w_g2    = (const float*)d_in[18];
  const float* b_g2    = (const float*)d_in[19];

  float* ws    = (float*)d_ws;
  float* XT    = ws + 0;               // 8192*512
  float* PRE   = ws + 4194304;         // 8192*512
  float* INPC  = ws + 8388608;         // 8192*512
  float* Hbuf  = ws + 12582912;        // 8192*512
  float* G1    = ws + 0;               // reuse XT+PRE after scan (8192*1024)
  float* LOGB  = ws + 8388608;         // reuse INPC (8192*128)
  float* SM    = ws + 9437184;         // 8192*128
  float* biwc  = ws + 16777216;        // 512
  u64*   exh   = (u64*)(ws + 16777728);// mirrors: 4*512 u64 each
  u64*   exf1  = (u64*)(ws + 16781824);
  u64*   exf2  = (u64*)(ws + 16785920);
  u64*   fexh  = (u64*)(ws + 16790016);// fast: 4*512 u64 each
  u64*   fexf1 = (u64*)(ws + 16794112);
  u64*   fexf2 = (u64*)(ws + 16798208);
  int*   ctl   = (int*)(ws + 16802304);// claim[4], nclaimed, pad, ready[4]
  if (ws_size < (size_t)16802368 * sizeof(float)) return;

  // reset mirror tags + claim/ready control (fast buffers self-poisoning)
  hipMemsetAsync(ws + 16777728, 0, 3 * 2048 * sizeof(u64), stream);
  hipMemsetAsync(ctl, 0, 16 * sizeof(int), stream);

  biwc_k<<<2, 256, 0, stream>>>(b_iw, input_b, biwc);
  gemm_k<false><<<dim3(8, 128), 256, 0, stream>>>(x, w_in, b_in, XT, NROW, 512, 4096);
  gemm_k<false><<<dim3(8, 128), 256, 0, stream>>>(XT, w_ff1, b_ff1, PRE, NROW, 512, 512);
  gemm_k<true ><<<dim3(8, 128), 256, 0, stream>>>(XT, w_iw, biwc, INPC, NROW, 512, 512);
  scan_k<<<2048, 256, 0, stream>>>(w_ff1, w_rw, w_ff2, w_ta, w_tb,
                                   b_ff2, b_ta, b_tb, r_b,
                                   PRE, INPC, Hbuf, exh, exf1, exf2,
                                   fexh, fexf1, fexf2, ctl);
  gemm_k<true ><<<dim3(16, 128), 256, 0, stream>>>(Hbuf, w_g1, b_g1, G1, NROW, 1024, 512);
  gemm_k<false><<<dim3(2, 128), 256, 0, stream>>>(G1, w_g2, b_g2, LOGB, NROW, 128, 1024);
  softmax_k<<<2048, 256, 0, stream>>>(LOGB, SM);
  smooth_topk_k<<<2048, 256, 0, stream>>>(SM, (float*)d_out);
}